// Round 7
// baseline (112.930 us; speedup 1.0000x reference)
//
#include <hip/hip_runtime.h>
#include <math.h>

// B=32, S=32, LQ=30, LS=40, D=300, F=256, FS=3, K=5
// out layout: [0]=total_loss, [1..1024]=sent_output(B,S), [1025..1056]=doc_em(B)

typedef __attribute__((ext_vector_type(4))) float f32x4;
typedef __attribute__((ext_vector_type(8))) short s16x8;

__device__ inline ushort bf16rne(float f) {
  unsigned u = __float_as_uint(f);
  u += 0x7fff + ((u >> 16) & 1);
  return (ushort)(u >> 16);
}
__device__ inline uint pack2(float a, float b) {
  return (uint)bf16rne(a) | ((uint)bf16rne(b) << 16);
}
__device__ inline float ubf(short h) { return __uint_as_float(((uint)(ushort)h) << 16); }

// Pack filters into MFMA B-fragment-major layout:
// fB[((tap*10+kstep)*16 + nt)*64 + lane][8] ; B[k][col]: col=lane&15, k=(lane>>4)*8+i
__global__ __launch_bounds__(64) void k_prepB(const float* __restrict__ filters,
                                              ushort* __restrict__ fB) {
  const int bid = blockIdx.x;            // (tap*10+kstep)*16 + nt, 480 total
  const int lane = threadIdx.x;
  const int nt = bid & 15;
  const int tk = bid >> 4;
  const int tap = tk / 10, kstep = tk - tap * 10;
  const int f = nt * 16 + (lane & 15);
  const int kb = kstep * 32 + (lane >> 4) * 8;
  uint p[4];
#pragma unroll
  for (int h = 0; h < 4; ++h) {
    int d0 = kb + h * 2, d1 = kb + h * 2 + 1;
    float v0 = (d0 < 300) ? filters[(size_t)f * 900 + tap * 300 + d0] : 0.f;
    float v1 = (d1 < 300) ? filters[(size_t)f * 900 + tap * 300 + d1] : 0.f;
    p[h] = (uint)bf16rne(v0) | ((uint)bf16rne(v1) << 16);
  }
  uint4* dst = (uint4*)(fB + ((size_t)bid * 64 + lane) * 8);
  *dst = make_uint4(p[0], p[1], p[2], p[3]);
}

// Question-side conv (32 blocks): emits qe/qc fragment blobs + row-norm rcps.
template<int L, int MT, int ROWS_ST>
__global__ __launch_bounds__(256) void k_conv_mfma(const int* __restrict__ tokens,
                                                   const float* __restrict__ embeds,
                                                   const ushort* __restrict__ fB,
                                                   ushort* __restrict__ blobA,
                                                   ushort* __restrict__ blobC,
                                                   float* __restrict__ rcpA,
                                                   float* __restrict__ rcpC) {
  constexpr int R320 = ROWS_ST * 320;
  __shared__ __align__(16) ushort xs[R320];
  __shared__ int tok[64];
  const int tid = threadIdx.x;
  const int seq = blockIdx.x;

  if (tid < L) tok[tid] = tokens[(size_t)seq * L + tid];
  __syncthreads();

  for (int idx = tid; idx < ROWS_ST * 80; idx += 256) {
    int row = idx / 80;
    int s = idx - row * 80;
    int d = s * 4;
    float4 v = make_float4(0.f, 0.f, 0.f, 0.f);
    if (row < L && d < 300) v = *(const float4*)(embeds + (size_t)tok[row] * 300 + d);
    int flat = row * 320 + d;
    int swz = flat ^ ((row & 7) << 3);
    *(uint2*)(xs + swz) = make_uint2(pack2(v.x, v.y), pack2(v.z, v.w));
  }
  __syncthreads();

  const int wv = tid >> 6, lane = tid & 63;
  const int lr = lane & 15, lh = lane >> 4;

  for (int t = wv; t < 10 * MT; t += 4) {
    int kstep = t / MT, tile = t - kstep * MT;
    int row = tile * 16 + lr;
    int flat = row * 320 + kstep * 32 + lh * 8;
    s16x8 v = *(const s16x8*)(xs + (flat ^ ((row & 7) << 3)));
    *(s16x8*)(blobA + ((((size_t)seq * 10 + kstep) * MT + tile) * 64 + lane) * 8) = v;
  }
  if (tid < L) {
    int row = tid;
    float s = 0.f;
    for (int c = 0; c < 40; ++c) {
      int flat = row * 320 + c * 8;
      s16x8 v = *(const s16x8*)(xs + (flat ^ ((row & 7) << 3)));
#pragma unroll
      for (int i = 0; i < 8; ++i) { float f = ubf(v[i]); s += f * f; }
    }
    rcpA[(size_t)seq * L + row] = (s > 0.f) ? rsqrtf(s) : 0.f;
  }

  f32x4 acc[MT][4];
#pragma unroll
  for (int mt = 0; mt < MT; ++mt)
#pragma unroll
    for (int n = 0; n < 4; ++n)
#pragma unroll
      for (int r = 0; r < 4; ++r) acc[mt][n][r] = 0.f;

  const s16x8* fBv = (const s16x8*)fB;
  for (int kstep = 0; kstep < 10; ++kstep) {
#pragma unroll
    for (int tap = 0; tap < 3; ++tap) {
      s16x8 b[4];
#pragma unroll
      for (int n = 0; n < 4; ++n)
        b[n] = fBv[((size_t)((tap * 10 + kstep) * 16 + (wv * 4 + n))) * 64 + lane];
#pragma unroll
      for (int mt = 0; mt < MT; ++mt) {
        int row = mt * 16 + lr + tap;
        int flat = row * 320 + kstep * 32 + lh * 8;
        s16x8 a = *(const s16x8*)(xs + (flat ^ ((row & 7) << 3)));
#pragma unroll
        for (int n = 0; n < 4; ++n)
          acc[mt][n] = __builtin_amdgcn_mfma_f32_16x16x32_bf16(a, b[n], acc[mt][n], 0, 0, 0);
      }
    }
  }
  __syncthreads();

#pragma unroll
  for (int mt = 0; mt < MT; ++mt)
#pragma unroll
    for (int n = 0; n < 4; ++n)
#pragma unroll
      for (int r = 0; r < 4; ++r) {
        int j = mt * 16 + lh * 4 + r;
        if (j < L) {
          int f = wv * 64 + n * 16 + lr;
          int flat = j * 320 + f;
          xs[flat ^ ((j & 7) << 3)] = bf16rne(acc[mt][n][r]);
        }
      }
  __syncthreads();

  for (int t = wv; t < 8 * MT; t += 4) {
    int kstep = t / MT, tile = t - kstep * MT;
    int row = tile * 16 + lr;
    int flat = row * 320 + kstep * 32 + lh * 8;
    s16x8 v = *(const s16x8*)(xs + (flat ^ ((row & 7) << 3)));
    *(s16x8*)(blobC + ((((size_t)seq * 8 + kstep) * MT + tile) * 64 + lane) * 8) = v;
  }
  if (tid < L) {
    int row = tid;
    float s = 0.f;
    for (int c = 0; c < 32; ++c) {
      int flat = row * 320 + c * 8;
      s16x8 v = *(const s16x8*)(xs + (flat ^ ((row & 7) << 3)));
#pragma unroll
      for (int i = 0; i < 8; ++i) { float f = ubf(v[i]); s += f * f; }
    }
    rcpC[(size_t)seq * L + row] = (s > 0.f) ? rsqrtf(s) : 0.f;
  }
}

// Fused sentence pipeline: one block per (b,s).
// stage se -> sim0 (qe x se, from xs) + rS0 -> conv MFMA -> writeback sc into xs
// -> sim1 (qc x sc) + rS1 -> top-5 pooling -> sigmoid -> mean -> out[1+bs]
__global__ __launch_bounds__(256) void k_fused(const int* __restrict__ sentences,
                                               const float* __restrict__ embeds,
                                               const ushort* __restrict__ fB,
                                               const ushort* __restrict__ qeb,
                                               const ushort* __restrict__ qcb,
                                               const float* __restrict__ rq0,
                                               const float* __restrict__ rq1,
                                               const float* __restrict__ oneh,
                                               const float* __restrict__ lin_w,
                                               const float* __restrict__ lin_b,
                                               float* __restrict__ out) {
  constexpr int L = 40, MT = 3, ROWS_ST = 50;
  constexpr int R320 = ROWS_ST * 320;
  __shared__ __align__(16) ushort xs[R320];      // 32 KB
  __shared__ int tok[48];
  __shared__ float simb[2][30][49];              // 11.8 KB, stride-49 pooling
  __shared__ float ohl[30 * 41];                 // 4.9 KB
  __shared__ float rQ[2][30], rS[2][40];
  __shared__ float feats[30][6];
  __shared__ float lo[30];

  const int bs = blockIdx.x;
  const int b = bs >> 5;
  const int tid = threadIdx.x;
  const int wv = tid >> 6, lane = tid & 63;
  const int lr = lane & 15, lh = lane >> 4;

  if (tid < 40) tok[tid] = sentences[(size_t)bs * 40 + tid];
  else if (tid >= 64 && tid < 94) rQ[0][tid - 64] = rq0[b * 30 + (tid - 64)];
  else if (tid >= 96 && tid < 126) rQ[1][tid - 96] = rq1[b * 30 + (tid - 96)];
  {
    const float* og = oneh + (size_t)bs * 1200;
    for (int i = tid; i < 1200; i += 256) {
      int q = i / 40, l = i - q * 40;
      ohl[q * 41 + l] = og[i];
    }
  }
  __syncthreads();

  // ---- stage se rows as bf16, swizzled, zero-padded ----
  for (int idx = tid; idx < ROWS_ST * 80; idx += 256) {
    int row = idx / 80;
    int s = idx - row * 80;
    int d = s * 4;
    float4 v = make_float4(0.f, 0.f, 0.f, 0.f);
    if (row < L && d < 300) v = *(const float4*)(embeds + (size_t)tok[row] * 300 + d);
    int flat = row * 320 + d;
    int swz = flat ^ ((row & 7) << 3);
    *(uint2*)(xs + swz) = make_uint2(pack2(v.x, v.y), pack2(v.z, v.w));
  }
  __syncthreads();

  // ---- phase 0: waves 0-2 sim MFMA (B-frags from xs), wave 3 rS0 norms ----
  f32x4 s0a = {0.f, 0.f, 0.f, 0.f}, s0b = {0.f, 0.f, 0.f, 0.f};
  if (wv < 3) {
    const ushort* Ab = qeb + (size_t)b * 10 * 2 * 512;
    for (int k = 0; k < 10; ++k) {
      int brow = wv * 16 + lr;
      int bflat = brow * 320 + k * 32 + lh * 8;
      s16x8 bf = *(const s16x8*)(xs + (bflat ^ ((brow & 7) << 3)));
      s16x8 a0 = *(const s16x8*)(Ab + ((size_t)(k * 2 + 0) * 64 + lane) * 8);
      s16x8 a1 = *(const s16x8*)(Ab + ((size_t)(k * 2 + 1) * 64 + lane) * 8);
      s0a = __builtin_amdgcn_mfma_f32_16x16x32_bf16(a0, bf, s0a, 0, 0, 0);
      s0b = __builtin_amdgcn_mfma_f32_16x16x32_bf16(a1, bf, s0b, 0, 0, 0);
    }
  } else if (lane < 40) {
    float s = 0.f;
    for (int c = 0; c < 40; ++c) {
      int flat = lane * 320 + c * 8;
      s16x8 v = *(const s16x8*)(xs + (flat ^ ((lane & 7) << 3)));
#pragma unroll
      for (int i = 0; i < 8; ++i) { float f = ubf(v[i]); s += f * f; }
    }
    rS[0][lane] = (s > 0.f) ? rsqrtf(s) : 0.f;
  }
  __syncthreads();   // rS0 ready; sim0 accs in regs
  if (wv < 3) {
    int l = wv * 16 + lr;
    if (l < 40) {
#pragma unroll
      for (int r = 0; r < 4; ++r) {
        int q0 = lh * 4 + r;
        simb[0][q0][l] = s0a[r] * rQ[0][q0] * rS[0][l];
        int q1 = 16 + lh * 4 + r;
        if (q1 < 30) simb[0][q1][l] = s0b[r] * rQ[0][q1] * rS[0][l];
      }
    }
  }

  // ---- conv MFMA (all 4 waves) ----
  f32x4 acc[MT][4];
#pragma unroll
  for (int mt = 0; mt < MT; ++mt)
#pragma unroll
    for (int n = 0; n < 4; ++n)
#pragma unroll
      for (int r = 0; r < 4; ++r) acc[mt][n][r] = 0.f;

  const s16x8* fBv = (const s16x8*)fB;
  for (int kstep = 0; kstep < 10; ++kstep) {
#pragma unroll
    for (int tap = 0; tap < 3; ++tap) {
      s16x8 bb[4];
#pragma unroll
      for (int n = 0; n < 4; ++n)
        bb[n] = fBv[((size_t)((tap * 10 + kstep) * 16 + (wv * 4 + n))) * 64 + lane];
#pragma unroll
      for (int mt = 0; mt < MT; ++mt) {
        int row = mt * 16 + lr + tap;
        int flat = row * 320 + kstep * 32 + lh * 8;
        s16x8 a = *(const s16x8*)(xs + (flat ^ ((row & 7) << 3)));
#pragma unroll
        for (int n = 0; n < 4; ++n)
          acc[mt][n] = __builtin_amdgcn_mfma_f32_16x16x32_bf16(a, bb[n], acc[mt][n], 0, 0, 0);
      }
    }
  }
  __syncthreads();   // all xs readers (sim0 B-frags, norms, conv A-frags) done

  // ---- write conv output back into xs as bf16 (rows j<L, cols<256) ----
#pragma unroll
  for (int mt = 0; mt < MT; ++mt)
#pragma unroll
    for (int n = 0; n < 4; ++n)
#pragma unroll
      for (int r = 0; r < 4; ++r) {
        int j = mt * 16 + lh * 4 + r;
        if (j < L) {
          int f = wv * 64 + n * 16 + lr;
          int flat = j * 320 + f;
          xs[flat ^ ((j & 7) << 3)] = bf16rne(acc[mt][n][r]);
        }
      }
  __syncthreads();

  // ---- phase 1: waves 0-2 sim MFMA (sc from xs, qc from blob), wave 3 rS1 ----
  f32x4 s1a = {0.f, 0.f, 0.f, 0.f}, s1b = {0.f, 0.f, 0.f, 0.f};
  if (wv < 3) {
    const ushort* Ab = qcb + (size_t)b * 8 * 2 * 512;
    for (int k = 0; k < 8; ++k) {
      int brow = wv * 16 + lr;
      int bflat = brow * 320 + k * 32 + lh * 8;
      s16x8 bf = *(const s16x8*)(xs + (bflat ^ ((brow & 7) << 3)));
      s16x8 a0 = *(const s16x8*)(Ab + ((size_t)(k * 2 + 0) * 64 + lane) * 8);
      s16x8 a1 = *(const s16x8*)(Ab + ((size_t)(k * 2 + 1) * 64 + lane) * 8);
      s1a = __builtin_amdgcn_mfma_f32_16x16x32_bf16(a0, bf, s1a, 0, 0, 0);
      s1b = __builtin_amdgcn_mfma_f32_16x16x32_bf16(a1, bf, s1b, 0, 0, 0);
    }
  } else if (lane < 40) {
    float s = 0.f;
    for (int c = 0; c < 32; ++c) {
      int flat = lane * 320 + c * 8;
      s16x8 v = *(const s16x8*)(xs + (flat ^ ((lane & 7) << 3)));
#pragma unroll
      for (int i = 0; i < 8; ++i) { float f = ubf(v[i]); s += f * f; }
    }
    rS[1][lane] = (s > 0.f) ? rsqrtf(s) : 0.f;
  }
  __syncthreads();   // rS1 ready
  if (wv < 3) {
    int l = wv * 16 + lr;
    if (l < 40) {
#pragma unroll
      for (int r = 0; r < 4; ++r) {
        int q0 = lh * 4 + r;
        simb[1][q0][l] = s1a[r] * rQ[1][q0] * rS[1][l];
        int q1 = 16 + lh * 4 + r;
        if (q1 < 30) simb[1][q1][l] = s1b[r] * rQ[1][q1] * rS[1][l];
      }
    }
  }
  __syncthreads();

  // ---- duplicate-safe top-5 pooling on 90 threads ----
  if (tid < 90) {
    const int m = tid / 30, q = tid - m * 30;
    const float* row = (m == 0) ? &simb[0][q][0] : (m == 1) ? &simb[1][q][0] : (ohl + q * 41);
    float thr = 3.4e38f;
    int got = 0;
    float sum = 0.f, maxv = 0.f;
    while (got < 5) {
      float mx = -3.4e38f;
      int c = 0;
      for (int l = 0; l < 40; ++l) {
        float v = row[l];
        if (v < thr) {
          if (v > mx) { mx = v; c = 1; }
          else if (v == mx) { c++; }
        }
      }
      if (c == 0) break;  // safety: never hang
      if (got == 0) maxv = mx;
      int take = (c < 5 - got) ? c : (5 - got);
      sum += mx * (float)take;
      got += take;
      thr = mx;
    }
    feats[q][m * 2 + 0] = maxv;
    feats[q][m * 2 + 1] = sum * 0.2f;
  }
  __syncthreads();
  if (tid < 30) {
    float z = lin_b[0];
#pragma unroll
    for (int i = 0; i < 6; ++i) z += feats[tid][i] * lin_w[i];
    lo[tid] = 1.0f / (1.0f + expf(-z));
  }
  __syncthreads();
  if (tid == 0) {
    float sum = 0.f;
    for (int q = 0; q < 30; ++q) sum += lo[q];
    out[1 + bs] = sum * (1.0f / 30.0f);
  }
}

__global__ __launch_bounds__(256) void k_loss(const int* __restrict__ tsent,
                                              const int* __restrict__ tdoc,
                                              float* __restrict__ out) {
  __shared__ float red[256];
  __shared__ float sent_loss_sh;
  const int tid = threadIdx.x;
  float local = 0.f;
  for (int i = tid; i < 1024; i += 256) {
    float p = out[1 + i];
    float t = (float)tsent[i];
    float lp = fmaxf(logf(p), -100.f);
    float l1 = fmaxf(logf(1.f - p), -100.f);
    local += -(t * lp + (1.f - t) * l1);
  }
  red[tid] = local;
  __syncthreads();
  for (int off = 128; off > 0; off >>= 1) {
    if (tid < off) red[tid] += red[tid + off];
    __syncthreads();
  }
  if (tid == 0) sent_loss_sh = red[0] * (1.0f / 1024.0f);
  __syncthreads();
  float dterm = 0.f;
  if (tid < 32) {
    float mx = out[1 + tid * 32];
    for (int s2 = 1; s2 < 32; ++s2) mx = fmaxf(mx, out[1 + tid * 32 + s2]);
    out[1025 + tid] = mx;
    float t = (float)tdoc[tid];
    float lp = fmaxf(logf(mx), -100.f);
    float l1 = fmaxf(logf(1.f - mx), -100.f);
    dterm = -(t * lp + (1.f - t) * l1);
  }
  red[tid] = dterm;
  __syncthreads();
  for (int off = 128; off > 0; off >>= 1) {
    if (tid < off) red[tid] += red[tid + off];
    __syncthreads();
  }
  if (tid == 0) out[0] = 0.5f * (sent_loss_sh + red[0] * (1.0f / 32.0f));
}

extern "C" void kernel_launch(void* const* d_in, const int* in_sizes, int n_in,
                              void* d_out, int out_size, void* d_ws, size_t ws_size,
                              hipStream_t stream) {
  const int*   question     = (const int*)d_in[0];
  const int*   sentences    = (const int*)d_in[1];
  const int*   target_sents = (const int*)d_in[2];
  const int*   target_docs  = (const int*)d_in[3];
  const float* oneh         = (const float*)d_in[4];
  const float* embeds       = (const float*)d_in[5];
  const float* filters      = (const float*)d_in[6];
  const float* lin_w        = (const float*)d_in[7];
  const float* lin_b        = (const float*)d_in[8];
  float* out = (float*)d_out;

  // workspace layout (all tiny now):
  ushort* fB  = (ushort*)d_ws;             // 480*64*8      = 245,760 ush (491.5 KB)
  ushort* qeb = fB  + 245760;              // 32*10*2*512   = 327,680 ush
  ushort* qcb = qeb + 327680;              // 32*8*2*512    = 262,144 ush
  float*  rq0 = (float*)(qcb + 262144);    // 32*30
  float*  rq1 = rq0 + 960;                 // 32*30

  k_prepB<<<480, 64, 0, stream>>>(filters, fB);
  k_conv_mfma<30, 2, 34><<<32, 256, 0, stream>>>(question, embeds, fB, qeb, qcb, rq0, rq1);
  k_fused<<<1024, 256, 0, stream>>>(sentences, embeds, fB, qeb, qcb, rq0, rq1,
                                    oneh, lin_w, lin_b, out);
  k_loss<<<1, 256, 0, stream>>>(target_sents, target_docs, out);
}